// Round 2
// baseline (271.216 us; speedup 1.0000x reference)
//
#include <hip/hip_runtime.h>

// SCVC: out[n, g*OG+o, p, q] = C[g,o]*x[n,g,p]*y[n,g,q]
//                              + wA[g,o,0]*x[n,g,p-1] + wA[g,o,1]*x[n,g,p+1]
//                              + wB[g,o,0]*y[n,g,q-1] + wB[g,o,1]*y[n,g,q+1]
// Shapes: N=8, G=8, OG=16, DX=DY=256. Output fp32, 268 MB -> store-BW-bound.

#define N_  8
#define G_  8
#define OG_ 16
#define DX_ 256
#define DY_ 256

// Native clang vector type: __builtin_nontemporal_store rejects the
// HIP_vector_type<float,4> class, needs scalar or ext_vector_type.
typedef float vfloat4 __attribute__((ext_vector_type(4)));

__global__ __launch_bounds__(256) void scvc_kernel(
    const float* __restrict__ x,   // (N, G, DX)
    const float* __restrict__ y,   // (N, G, DY)
    const float* __restrict__ C,   // (G, OG)
    const float* __restrict__ wA,  // (G, OG, 2)
    const float* __restrict__ wB,  // (G, OG, 2)
    float* __restrict__ out)       // (N, G*OG, DX, DY)
{
    __shared__ float sarr[DX_];   // C[g,o] * x[n,g,p]
    __shared__ float aarr[DX_];   // wA0*x[p-1] + wA1*x[p+1]
    __shared__ float ybuf[DY_];   // y[n,g,q]
    __shared__ float bbuf[DY_];   // wB0*y[q-1] + wB1*y[q+1]

    const int t   = blockIdx.x;          // 0 .. N*G*OG-1, matches out channel-major order
    const int n   = t / (G_ * OG_);
    const int rem = t % (G_ * OG_);
    const int g   = rem / OG_;
    const int o   = rem % OG_;

    const int tid = threadIdx.x;

    const int go = g * OG_ + o;
    const float co  = C[go];
    const float wa0 = wA[go * 2 + 0];
    const float wa1 = wA[go * 2 + 1];
    const float wb0 = wB[go * 2 + 0];
    const float wb1 = wB[go * 2 + 1];

    const float* xrow = x + (size_t)(n * G_ + g) * DX_;
    const float* yrow = y + (size_t)(n * G_ + g) * DY_;

    // One-time per-block staging (256 threads cover DX_=DY_=256).
    {
        float xv = xrow[tid];
        float xl = (tid > 0)       ? xrow[tid - 1] : 0.0f;
        float xr = (tid < DX_ - 1) ? xrow[tid + 1] : 0.0f;
        sarr[tid] = co * xv;
        aarr[tid] = wa0 * xl + wa1 * xr;

        float yv = yrow[tid];
        float yl = (tid > 0)       ? yrow[tid - 1] : 0.0f;
        float yr = (tid < DY_ - 1) ? yrow[tid + 1] : 0.0f;
        ybuf[tid] = yv;
        bbuf[tid] = wb0 * yl + wb1 * yr;
    }
    __syncthreads();

    // Each thread owns a float4 at q = qv*4 (held in registers), covers rows
    // p = pr, pr+4, pr+8, ... Wave lanes share p -> sarr/aarr reads are
    // wave-uniform LDS broadcasts (free).
    const int qv = tid & 63;
    const int pr = tid >> 6;

    const vfloat4 y4 = ((const vfloat4*)ybuf)[qv];
    const vfloat4 b4 = ((const vfloat4*)bbuf)[qv];

    float* obase = out + (size_t)t * (DX_ * DY_);

#pragma unroll 4
    for (int pb = 0; pb < DX_; pb += 4) {
        const int p  = pb + pr;
        const float s  = sarr[p];
        const float av = aarr[p];
        vfloat4 v;
        v.x = fmaf(s, y4.x, av + b4.x);
        v.y = fmaf(s, y4.y, av + b4.y);
        v.z = fmaf(s, y4.z, av + b4.z);
        v.w = fmaf(s, y4.w, av + b4.w);
        __builtin_nontemporal_store(v, (vfloat4*)(obase + (size_t)p * DY_) + qv);
    }
}

extern "C" void kernel_launch(void* const* d_in, const int* in_sizes, int n_in,
                              void* d_out, int out_size, void* d_ws, size_t ws_size,
                              hipStream_t stream) {
    const float* x  = (const float*)d_in[0];
    const float* y  = (const float*)d_in[1];
    const float* C  = (const float*)d_in[2];
    const float* wA = (const float*)d_in[3];
    const float* wB = (const float*)d_in[4];
    float* out = (float*)d_out;

    const int nblocks = N_ * G_ * OG_;  // 1024
    scvc_kernel<<<nblocks, 256, 0, stream>>>(x, y, C, wA, wB, out);
}

// Round 3
// 260.924 us; speedup vs baseline: 1.0394x; 1.0394x over previous
//
#include <hip/hip_runtime.h>

// SCVC: out[n, g*OG+o, p, q] = C[g,o]*x[n,g,p]*y[n,g,q]
//                              + wA[g,o,0]*x[n,g,p-1] + wA[g,o,1]*x[n,g,p+1]
//                              + wB[g,o,0]*y[n,g,q-1] + wB[g,o,1]*y[n,g,q+1]
// Shapes: N=8, G=8, OG=16, DX=DY=256. Output fp32, 268 MB -> store-BW-bound.
// R2: drop nontemporal stores (suspected write-BW de-rate vs plain stores
// through L2; harness fill kernel hits 6.4 TB/s with plain stores), and
// double grid to 2048 blocks (half-channel each) for latency hiding.

#define N_  8
#define G_  8
#define OG_ 16
#define DX_ 256
#define DY_ 256

typedef float vfloat4 __attribute__((ext_vector_type(4)));

__global__ __launch_bounds__(256) void scvc_kernel(
    const float* __restrict__ x,   // (N, G, DX)
    const float* __restrict__ y,   // (N, G, DY)
    const float* __restrict__ C,   // (G, OG)
    const float* __restrict__ wA,  // (G, OG, 2)
    const float* __restrict__ wB,  // (G, OG, 2)
    float* __restrict__ out)       // (N, G*OG, DX, DY)
{
    __shared__ float sarr[DX_];   // C[g,o] * x[n,g,p]
    __shared__ float aarr[DX_];   // wA0*x[p-1] + wA1*x[p+1]
    __shared__ float ybuf[DY_];   // y[n,g,q]
    __shared__ float bbuf[DY_];   // wB0*y[q-1] + wB1*y[q+1]

    const int t    = blockIdx.x >> 1;        // channel index 0 .. N*G*OG-1
    const int half = blockIdx.x & 1;         // which 128-row half of the image
    const int n   = t / (G_ * OG_);
    const int rem = t % (G_ * OG_);
    const int g   = rem / OG_;
    const int o   = rem % OG_;

    const int tid = threadIdx.x;

    const int go = g * OG_ + o;
    const float co  = C[go];
    const float wa0 = wA[go * 2 + 0];
    const float wa1 = wA[go * 2 + 1];
    const float wb0 = wB[go * 2 + 0];
    const float wb1 = wB[go * 2 + 1];

    const float* xrow = x + (size_t)(n * G_ + g) * DX_;
    const float* yrow = y + (size_t)(n * G_ + g) * DY_;

    // One-time per-block staging (256 threads cover DX_=DY_=256).
    {
        float xv = xrow[tid];
        float xl = (tid > 0)       ? xrow[tid - 1] : 0.0f;
        float xr = (tid < DX_ - 1) ? xrow[tid + 1] : 0.0f;
        sarr[tid] = co * xv;
        aarr[tid] = wa0 * xl + wa1 * xr;

        float yv = yrow[tid];
        float yl = (tid > 0)       ? yrow[tid - 1] : 0.0f;
        float yr = (tid < DY_ - 1) ? yrow[tid + 1] : 0.0f;
        ybuf[tid] = yv;
        bbuf[tid] = wb0 * yl + wb1 * yr;
    }
    __syncthreads();

    // Each thread owns a float4 at q = qv*4 (registers), covers rows
    // p = pbase+pr, pbase+pr+4, ... Wave lanes share p -> sarr/aarr reads
    // are wave-uniform LDS broadcasts.
    const int qv = tid & 63;
    const int pr = tid >> 6;
    const int pbase = half * (DX_ / 2);

    const vfloat4 y4 = ((const vfloat4*)ybuf)[qv];
    const vfloat4 b4 = ((const vfloat4*)bbuf)[qv];

    float* obase = out + (size_t)t * (DX_ * DY_);

#pragma unroll 4
    for (int pb = 0; pb < DX_ / 2; pb += 4) {
        const int p  = pbase + pb + pr;
        const float s  = sarr[p];
        const float av = aarr[p];
        vfloat4 v;
        v.x = fmaf(s, y4.x, av + b4.x);
        v.y = fmaf(s, y4.y, av + b4.y);
        v.z = fmaf(s, y4.z, av + b4.z);
        v.w = fmaf(s, y4.w, av + b4.w);
        ((vfloat4*)(obase + (size_t)p * DY_))[qv] = v;
    }
}

extern "C" void kernel_launch(void* const* d_in, const int* in_sizes, int n_in,
                              void* d_out, int out_size, void* d_ws, size_t ws_size,
                              hipStream_t stream) {
    const float* x  = (const float*)d_in[0];
    const float* y  = (const float*)d_in[1];
    const float* C  = (const float*)d_in[2];
    const float* wA = (const float*)d_in[3];
    const float* wB = (const float*)d_in[4];
    float* out = (float*)d_out;

    const int nblocks = N_ * G_ * OG_ * 2;  // 2048
    scvc_kernel<<<nblocks, 256, 0, stream>>>(x, y, C, wA, wB, out);
}